// Round 4
// baseline (458.878 us; speedup 1.0000x reference)
//
#include <hip/hip_runtime.h>
#include <cmath>

// Problem constants
#define BB 64
#define TT 128
#define SS 512
#define EE 1024
#define DDIM 512
#define NEG_INF_F (-1.0e10f)

// MFMA tiling
#define BM 128
#define BN 64
#define BNS 32   // narrow N-tile for grid-limited kernels (k_energy, k_out)
#define BK 32
#define LDSTP 20   // padded layout row stride (dwords)
#define ROWU 32    // swizzled plane layout row stride in u16 (64 B/row)

typedef unsigned short u16;
typedef __attribute__((ext_vector_type(8))) short bf16x8;
typedef __attribute__((ext_vector_type(4))) float f32x4;

// ---------------------------------------------------------------------------
// fp32 -> bf16 split (hi = rne(f), lo = rne(f - hi)); ~2^-18 rel error
// ---------------------------------------------------------------------------
__device__ __forceinline__ unsigned bf16_rne(float f) {
    unsigned u = __float_as_uint(f);
    return (u + 0x7fffu + ((u >> 16) & 1u)) >> 16;
}
__device__ __forceinline__ void split2(float f, unsigned& h, unsigned& l) {
    h = bf16_rne(f);
    float fh = __uint_as_float(h << 16);
    l = bf16_rne(f - fh);
}

// ---------------------------------------------------------------------------
// glds staging of a bf16 plane tile: ROWS rows x 32 bf16 (64 B/row), quad-swizzle
// chunk q -> slot q^((r>>1)&3). LDS base wave-uniform, lane-linear 16 B writes.
// ---------------------------------------------------------------------------
template <int ROWS>
__device__ __forceinline__ void stage_glds(u16* lds, const u16* __restrict__ src,
                                           int ld, int tid) {
    const int w = tid >> 6, lane = tid & 63;
    const int rl = lane >> 2, p = lane & 3;
#pragma unroll
    for (int i = 0; i < ROWS / 64; ++i) {
        const int r0 = (w + 4 * i) * 16;
        const int r = r0 + rl;
        const int q = p ^ ((r >> 1) & 3);
        const u16* g = src + (size_t)r * ld + 8 * q;
        __builtin_amdgcn_global_load_lds(
            (const __attribute__((address_space(1))) unsigned*)g,
            (__attribute__((address_space(3))) unsigned*)(lds + r0 * ROWU),
            16, 0, 0);
    }
}

// 32-row hi+lo pair staged by 4 waves (waves 0-1: hi, waves 2-3: lo)
__device__ __forceinline__ void stage_glds_b32(u16* ldsh, u16* ldsl,
                                               const u16* __restrict__ hsrc,
                                               const u16* __restrict__ lsrc,
                                               int ld, int tid) {
    const int w = tid >> 6, lane = tid & 63;
    const int rl = lane >> 2, p = lane & 3;
    const int r0 = (w & 1) * 16;
    const int r = r0 + rl;
    const int q = p ^ ((r >> 1) & 3);
    const u16* src = (w < 2) ? hsrc : lsrc;
    u16* lds = (w < 2) ? ldsh : ldsl;
    __builtin_amdgcn_global_load_lds(
        (const __attribute__((address_space(1))) unsigned*)(src + (size_t)r * ld + 8 * q),
        (__attribute__((address_space(3))) unsigned*)(lds + r0 * ROWU),
        16, 0, 0);
}

// Read a 16x16x32 fragment from the swizzled plane layout (one ds_read_b128)
__device__ __forceinline__ bf16x8 read_frag_sw(const u16* buf, int row, int q) {
    const int c = q ^ ((row >> 1) & 3);
    return *(const bf16x8*)(buf + row * ROWU + 8 * c);
}

// ---------------------------------------------------------------------------
// VALU staging of an NT fp32 operand (rows x BK) into padded hi/lo LDS
// ---------------------------------------------------------------------------
template <int ROWS>
__device__ __forceinline__ void stage_nt(unsigned* hi, unsigned* lo,
                                         const float* __restrict__ src, int ld, int tid) {
#pragma unroll
    for (int i = 0; i < ROWS / 32; ++i) {
        int s = tid + 256 * i;
        int r = s >> 3, kq = s & 7;
        float4 v = *(const float4*)(src + (size_t)r * ld + 4 * kq);
        unsigned h0, l0, h1, l1, h2, l2, h3, l3;
        split2(v.x, h0, l0); split2(v.y, h1, l1);
        split2(v.z, h2, l2); split2(v.w, h3, l3);
        *(uint2*)&hi[r * LDSTP + 2 * kq] = make_uint2(h0 | (h1 << 16), h2 | (h3 << 16));
        *(uint2*)&lo[r * LDSTP + 2 * kq] = make_uint2(l0 | (l1 << 16), l2 | (l3 << 16));
    }
}

// ---------------------------------------------------------------------------
// VALU staging of a transposed fp32 B tile (k_ctx): [BK k][BN n] -> LDS rows n
// ---------------------------------------------------------------------------
__device__ __forceinline__ void stage_tr(unsigned* hi, unsigned* lo,
                                         const float* __restrict__ src, int ld, int tid) {
    int eq = tid & 15;   // n quad
    int sp = tid >> 4;   // k pair
    const float* p = src + (size_t)(2 * sp) * ld + 4 * eq;
    float4 va = *(const float4*)p;
    float4 vb = *(const float4*)(p + ld);
    float av[4] = {va.x, va.y, va.z, va.w};
    float bv[4] = {vb.x, vb.y, vb.z, vb.w};
#pragma unroll
    for (int c = 0; c < 4; ++c) {
        unsigned ha, la, hb, lb;
        split2(av[c], ha, la);
        split2(bv[c], hb, lb);
        hi[(4 * eq + c) * LDSTP + sp] = ha | (hb << 16);
        lo[(4 * eq + c) * LDSTP + sp] = la | (lb << 16);
    }
}

__device__ __forceinline__ bf16x8 read_frag_pad(const unsigned* buf, int row, int q) {
    return *(const bf16x8*)(buf + row * LDSTP + 4 * q);
}

// ---------------------------------------------------------------------------
// Split-bf16 MFMA cores (3 MFMAs per 16x16 tile)
// ---------------------------------------------------------------------------
__device__ __forceinline__ void mfma_ss(const u16* Ah, const u16* Al,
                                        const u16* Bh, const u16* Bl,
                                        f32x4 acc[4][2], int tid) {
    const int lane = tid & 63, w = tid >> 6;
    const int wm = (w & 1) * 64, wn = (w >> 1) * 32;
    const int fr = lane & 15, q = lane >> 4;
    bf16x8 ah[4], al[4];
#pragma unroll
    for (int i = 0; i < 4; ++i) {
        ah[i] = read_frag_sw(Ah, wm + 16 * i + fr, q);
        al[i] = read_frag_sw(Al, wm + 16 * i + fr, q);
    }
#pragma unroll
    for (int j = 0; j < 2; ++j) {
        bf16x8 bh = read_frag_sw(Bh, wn + 16 * j + fr, q);
        bf16x8 bl = read_frag_sw(Bl, wn + 16 * j + fr, q);
#pragma unroll
        for (int i = 0; i < 4; ++i) {
            acc[i][j] = __builtin_amdgcn_mfma_f32_16x16x32_bf16(ah[i], bh, acc[i][j], 0, 0, 0);
            acc[i][j] = __builtin_amdgcn_mfma_f32_16x16x32_bf16(ah[i], bl, acc[i][j], 0, 0, 0);
            acc[i][j] = __builtin_amdgcn_mfma_f32_16x16x32_bf16(al[i], bh, acc[i][j], 0, 0, 0);
        }
    }
}

// 64x16 wave tile, B in padded layout (k_energy)
__device__ __forceinline__ void mfma_sp41(const u16* Ah, const u16* Al,
                                          const unsigned* Bh, const unsigned* Bl,
                                          f32x4 acc[4], int tid) {
    const int lane = tid & 63, w = tid >> 6;
    const int wm = (w & 1) * 64, wn = (w >> 1) * 16;
    const int fr = lane & 15, q = lane >> 4;
    bf16x8 ah[4], al[4];
#pragma unroll
    for (int i = 0; i < 4; ++i) {
        ah[i] = read_frag_sw(Ah, wm + 16 * i + fr, q);
        al[i] = read_frag_sw(Al, wm + 16 * i + fr, q);
    }
    bf16x8 bh = read_frag_pad(Bh, wn + fr, q);
    bf16x8 bl = read_frag_pad(Bl, wn + fr, q);
#pragma unroll
    for (int i = 0; i < 4; ++i) {
        acc[i] = __builtin_amdgcn_mfma_f32_16x16x32_bf16(ah[i], bh, acc[i], 0, 0, 0);
        acc[i] = __builtin_amdgcn_mfma_f32_16x16x32_bf16(ah[i], bl, acc[i], 0, 0, 0);
        acc[i] = __builtin_amdgcn_mfma_f32_16x16x32_bf16(al[i], bh, acc[i], 0, 0, 0);
    }
}

// 64x16 wave tile, B in swizzled plane layout (k_out)
__device__ __forceinline__ void mfma_ss41(const u16* Ah, const u16* Al,
                                          const u16* Bh, const u16* Bl,
                                          f32x4 acc[4], int tid) {
    const int lane = tid & 63, w = tid >> 6;
    const int wm = (w & 1) * 64, wn = (w >> 1) * 16;
    const int fr = lane & 15, q = lane >> 4;
    bf16x8 ah[4], al[4];
#pragma unroll
    for (int i = 0; i < 4; ++i) {
        ah[i] = read_frag_sw(Ah, wm + 16 * i + fr, q);
        al[i] = read_frag_sw(Al, wm + 16 * i + fr, q);
    }
    bf16x8 bh = read_frag_sw(Bh, wn + fr, q);
    bf16x8 bl = read_frag_sw(Bl, wn + fr, q);
#pragma unroll
    for (int i = 0; i < 4; ++i) {
        acc[i] = __builtin_amdgcn_mfma_f32_16x16x32_bf16(ah[i], bh, acc[i], 0, 0, 0);
        acc[i] = __builtin_amdgcn_mfma_f32_16x16x32_bf16(ah[i], bl, acc[i], 0, 0, 0);
        acc[i] = __builtin_amdgcn_mfma_f32_16x16x32_bf16(al[i], bh, acc[i], 0, 0, 0);
    }
}

// ---------------------------------------------------------------------------
// Convert kernels
// ---------------------------------------------------------------------------
__global__ __launch_bounds__(256) void k_conv(const float* __restrict__ src,
                                              u16* __restrict__ hi, u16* __restrict__ lo) {
    const int i = blockIdx.x * 256 + threadIdx.x;
    float4 v = ((const float4*)src)[i];
    unsigned h0, l0, h1, l1, h2, l2, h3, l3;
    split2(v.x, h0, l0); split2(v.y, h1, l1);
    split2(v.z, h2, l2); split2(v.w, h3, l3);
    ((ushort4*)hi)[i] = make_ushort4((u16)h0, (u16)h1, (u16)h2, (u16)h3);
    ((ushort4*)lo)[i] = make_ushort4((u16)l0, (u16)l1, (u16)l2, (u16)l3);
}

// Wo [1536,512] -> WoT planes [512,1536]
__global__ __launch_bounds__(256) void k_wot(const float* __restrict__ Wo,
                                             u16* __restrict__ thi, u16* __restrict__ tlo) {
    __shared__ float t[64][65];
    const int tid = threadIdx.x;
    const int r0 = blockIdx.x * 64;
    const int c0 = blockIdx.y * 64;
    const int rr = tid >> 4, cc = tid & 15;
#pragma unroll
    for (int i = 0; i < 4; ++i) {
        float4 v = *(const float4*)(Wo + (size_t)(r0 + rr + 16 * i) * DDIM + c0 + 4 * cc);
        t[rr + 16 * i][4 * cc + 0] = v.x;
        t[rr + 16 * i][4 * cc + 1] = v.y;
        t[rr + 16 * i][4 * cc + 2] = v.z;
        t[rr + 16 * i][4 * cc + 3] = v.w;
    }
    __syncthreads();
#pragma unroll
    for (int i = 0; i < 4; ++i) {
        const int oc = rr + 16 * i;
        unsigned h0, l0, h1, l1, h2, l2, h3, l3;
        split2(t[4 * cc + 0][oc], h0, l0);
        split2(t[4 * cc + 1][oc], h1, l1);
        split2(t[4 * cc + 2][oc], h2, l2);
        split2(t[4 * cc + 3][oc], h3, l3);
        size_t off = (size_t)(c0 + oc) * (EE + DDIM) + r0 + 4 * cc;
        *(ushort4*)(thi + off) = make_ushort4((u16)h0, (u16)h1, (u16)h2, (u16)h3);
        *(ushort4*)(tlo + off) = make_ushort4((u16)l0, (u16)l1, (u16)l2, (u16)l3);
    }
}

// ---------------------------------------------------------------------------
// K1: decW = dec @ W_attn^T (NT, M=8192, N=1024, K=512) -> hi/lo planes
// ---------------------------------------------------------------------------
__global__ __launch_bounds__(256) void k_decw(const u16* __restrict__ Ahp, const u16* __restrict__ Alp,
                                              const u16* __restrict__ Bhp, const u16* __restrict__ Blp,
                                              u16* __restrict__ Chi, u16* __restrict__ Clo) {
    __shared__ u16 Ah[BM * ROWU], Al[BM * ROWU], Bh[BN * ROWU], Bl[BN * ROWU];
    const int tid = threadIdx.x;
    const int bm = blockIdx.x * BM, bn = blockIdx.y * BN;
    f32x4 acc[4][2] = {};
    for (int k0 = 0; k0 < DDIM; k0 += BK) {
        __syncthreads();
        stage_glds<BM>(Ah, Ahp + (size_t)bm * DDIM + k0, DDIM, tid);
        stage_glds<BM>(Al, Alp + (size_t)bm * DDIM + k0, DDIM, tid);
        stage_glds<BN>(Bh, Bhp + (size_t)bn * DDIM + k0, DDIM, tid);
        stage_glds<BN>(Bl, Blp + (size_t)bn * DDIM + k0, DDIM, tid);
        __builtin_amdgcn_s_waitcnt(0);
        __syncthreads();
        mfma_ss(Ah, Al, Bh, Bl, acc, tid);
    }
    const int lane = tid & 63, w = tid >> 6;
    const int wm = (w & 1) * 64, wn = (w >> 1) * 32;
    const int fr = lane & 15, q = lane >> 4;
#pragma unroll
    for (int j = 0; j < 2; ++j) {
        const int col = bn + wn + 16 * j + fr;
#pragma unroll
        for (int i = 0; i < 4; ++i)
#pragma unroll
            for (int r = 0; r < 4; ++r) {
                const int row = bm + wm + 16 * i + 4 * q + r;
                unsigned h, l;
                split2(acc[i][j][r], h, l);
                Chi[(size_t)row * EE + col] = (u16)h;
                Clo[(size_t)row * EE + col] = (u16)l;
            }
    }
}

// ---------------------------------------------------------------------------
// K1b: decb[m] = dec[m,:] . b_attn
// ---------------------------------------------------------------------------
__global__ __launch_bounds__(256) void k_decb(const float* __restrict__ dec,
                                              const float* __restrict__ ba,
                                              float* __restrict__ decb) {
    const int row = blockIdx.x * 4 + (threadIdx.x >> 6);
    const int lane = threadIdx.x & 63;
    const float* x = dec + (size_t)row * DDIM;
    float s = 0.f;
#pragma unroll
    for (int i = 0; i < 8; ++i) {
        int idx = lane + i * 64;
        s += x[idx] * ba[idx];
    }
#pragma unroll
    for (int off = 32; off >= 1; off >>= 1) s += __shfl_xor(s, off, 64);
    if (lane == 0) decb[row] = s;
}

// ---------------------------------------------------------------------------
// K2: masked energies (NT batched, M=T=128, N=32-tile of S, K=E) + bias + mask
//     grid (S/32, 1, B) = 1024 blocks -> 4 blocks/CU
// ---------------------------------------------------------------------------
__global__ __launch_bounds__(256, 4) void k_energy(const u16* __restrict__ Ahp, const u16* __restrict__ Alp,
                                                   const float* __restrict__ enc,
                                                   const int* __restrict__ mask,
                                                   const float* __restrict__ decb,
                                                   float* __restrict__ menerg) {
    const int b = blockIdx.z;
    const int bn = blockIdx.x * BNS;
    __shared__ u16 Ah[BM * ROWU], Al[BM * ROWU];
    __shared__ unsigned Bh[BNS * LDSTP], Bl[BNS * LDSTP];
    const int tid = threadIdx.x;
    const u16* Abh = Ahp + (size_t)b * TT * EE;
    const u16* Abl = Alp + (size_t)b * TT * EE;
    const float* Bt = enc + (size_t)b * SS * EE + (size_t)bn * EE;
    f32x4 acc[4] = {};
    for (int k0 = 0; k0 < EE; k0 += BK) {
        __syncthreads();
        stage_glds<BM>(Ah, Abh + k0, EE, tid);
        stage_glds<BM>(Al, Abl + k0, EE, tid);
        stage_nt<BNS>(Bh, Bl, Bt + k0, EE, tid);
        __builtin_amdgcn_s_waitcnt(0);
        __syncthreads();
        mfma_sp41(Ah, Al, Bh, Bl, acc, tid);
    }
    const int lane = tid & 63, w = tid >> 6;
    const int wm = (w & 1) * 64, wn = (w >> 1) * 16;
    const int fr = lane & 15, q = lane >> 4;
    const int* mb = mask + (size_t)b * SS;
    const float* dbp = decb + (size_t)b * TT;
    float* Crow = menerg + (size_t)b * TT * SS;
    const int col = bn + wn + fr;
    const int mk = mb[col];
#pragma unroll
    for (int i = 0; i < 4; ++i) {
        float4 d4 = *(const float4*)(dbp + wm + 16 * i + 4 * q);
        float db[4] = {d4.x, d4.y, d4.z, d4.w};
#pragma unroll
        for (int r = 0; r < 4; ++r) {
            const int row = wm + 16 * i + 4 * q + r;
            Crow[(size_t)row * SS + col] = mk ? acc[i][r] + db[r] : NEG_INF_F;
        }
    }
}

// ---------------------------------------------------------------------------
// K3: softmax over S=512 -> attn fp32 (output) + attn hi/lo planes
// ---------------------------------------------------------------------------
__global__ __launch_bounds__(128) void k_softmax(const float* __restrict__ me,
                                                 float* __restrict__ attn,
                                                 u16* __restrict__ ahi,
                                                 u16* __restrict__ alo) {
    const int row = blockIdx.x;
    const int tid = threadIdx.x;
    const float4 v = ((const float4*)(me + (size_t)row * SS))[tid];
    float m = fmaxf(fmaxf(v.x, v.y), fmaxf(v.z, v.w));
#pragma unroll
    for (int off = 32; off >= 1; off >>= 1) m = fmaxf(m, __shfl_xor(m, off, 64));
    __shared__ float redm[2];
    __shared__ float reds[2];
    const int wv = tid >> 6, lane = tid & 63;
    if (lane == 0) redm[wv] = m;
    __syncthreads();
    m = fmaxf(redm[0], redm[1]);
    float e0 = __expf(v.x - m), e1 = __expf(v.y - m);
    float e2 = __expf(v.z - m), e3 = __expf(v.w - m);
    float s = (e0 + e1) + (e2 + e3);
#pragma unroll
    for (int off = 32; off >= 1; off >>= 1) s += __shfl_xor(s, off, 64);
    if (lane == 0) reds[wv] = s;
    __syncthreads();
    s = reds[0] + reds[1];
    const float inv = 1.0f / s;
    float o0 = e0 * inv, o1 = e1 * inv, o2 = e2 * inv, o3 = e3 * inv;
    ((float4*)(attn + (size_t)row * SS))[tid] = make_float4(o0, o1, o2, o3);
    unsigned h0, l0, h1, l1, h2, l2, h3, l3;
    split2(o0, h0, l0); split2(o1, h1, l1); split2(o2, h2, l2); split2(o3, h3, l3);
    ((ushort4*)(ahi + (size_t)row * SS))[tid] = make_ushort4((u16)h0, (u16)h1, (u16)h2, (u16)h3);
    ((ushort4*)(alo + (size_t)row * SS))[tid] = make_ushort4((u16)l0, (u16)l1, (u16)l2, (u16)l3);
}

// ---------------------------------------------------------------------------
// K4: wc = attn @ enc (NN batched, M=T, N=E, K=S) -> wc hi/lo planes
// ---------------------------------------------------------------------------
__global__ __launch_bounds__(256) void k_ctx(const u16* __restrict__ Ahp, const u16* __restrict__ Alp,
                                             const float* __restrict__ enc,
                                             u16* __restrict__ Chi, u16* __restrict__ Clo) {
    const int b = blockIdx.z;
    const int bn = blockIdx.x * BN;
    __shared__ u16 Ah[BM * ROWU], Al[BM * ROWU];
    __shared__ unsigned Bh[BN * LDSTP], Bl[BN * LDSTP];
    const int tid = threadIdx.x;
    const u16* Abh = Ahp + (size_t)b * TT * SS;
    const u16* Abl = Alp + (size_t)b * TT * SS;
    const float* Bm = enc + (size_t)b * SS * EE + bn;
    f32x4 acc[4][2] = {};
    for (int k0 = 0; k0 < SS; k0 += BK) {
        __syncthreads();
        stage_glds<BM>(Ah, Abh + k0, SS, tid);
        stage_glds<BM>(Al, Abl + k0, SS, tid);
        stage_tr(Bh, Bl, Bm + (size_t)k0 * EE, EE, tid);
        __builtin_amdgcn_s_waitcnt(0);
        __syncthreads();
        // B is padded-layout here; reuse mfma_sp via two 16-col halves
        {
            const int lane2 = tid & 63, w2 = tid >> 6;
            const int wm = (w2 & 1) * 64, wn = (w2 >> 1) * 32;
            const int fr = lane2 & 15, q = lane2 >> 4;
            bf16x8 ah[4], al[4];
#pragma unroll
            for (int i = 0; i < 4; ++i) {
                ah[i] = read_frag_sw(Ah, wm + 16 * i + fr, q);
                al[i] = read_frag_sw(Al, wm + 16 * i + fr, q);
            }
#pragma unroll
            for (int j = 0; j < 2; ++j) {
                bf16x8 bh = read_frag_pad(Bh, wn + 16 * j + fr, q);
                bf16x8 bl = read_frag_pad(Bl, wn + 16 * j + fr, q);
#pragma unroll
                for (int i = 0; i < 4; ++i) {
                    acc[i][j] = __builtin_amdgcn_mfma_f32_16x16x32_bf16(ah[i], bh, acc[i][j], 0, 0, 0);
                    acc[i][j] = __builtin_amdgcn_mfma_f32_16x16x32_bf16(ah[i], bl, acc[i][j], 0, 0, 0);
                    acc[i][j] = __builtin_amdgcn_mfma_f32_16x16x32_bf16(al[i], bh, acc[i][j], 0, 0, 0);
                }
            }
        }
    }
    const int lane = tid & 63, w = tid >> 6;
    const int wm = (w & 1) * 64, wn = (w >> 1) * 32;
    const int fr = lane & 15, q = lane >> 4;
    u16* Ch = Chi + (size_t)b * TT * EE;
    u16* Cl = Clo + (size_t)b * TT * EE;
#pragma unroll
    for (int j = 0; j < 2; ++j) {
        const int col = bn + wn + 16 * j + fr;
#pragma unroll
        for (int i = 0; i < 4; ++i)
#pragma unroll
            for (int r = 0; r < 4; ++r) {
                const int row = wm + 16 * i + 4 * q + r;
                unsigned h, l;
                split2(acc[i][j][r], h, l);
                Ch[(size_t)row * EE + col] = (u16)h;
                Cl[(size_t)row * EE + col] = (u16)l;
            }
    }
}

// ---------------------------------------------------------------------------
// K5: h_tilde = tanh([wc | dec] @ W_out) via WoT planes (NT, M=8192, N=512, K=1536)
//     BN=32 -> grid (64, 16) = 1024 blocks, 4 blocks/CU
// ---------------------------------------------------------------------------
__global__ __launch_bounds__(256, 4) void k_out(const u16* __restrict__ wch, const u16* __restrict__ wcl,
                                                const u16* __restrict__ dech, const u16* __restrict__ decl,
                                                const u16* __restrict__ woth, const u16* __restrict__ wotl,
                                                float* __restrict__ ht) {
    __shared__ u16 Ah[BM * ROWU], Al[BM * ROWU], Bh[BNS * ROWU], Bl[BNS * ROWU];
    const int tid = threadIdx.x;
    const int bm = blockIdx.x * BM, bn = blockIdx.y * BNS;
    f32x4 acc[4] = {};
    for (int k0 = 0; k0 < EE + DDIM; k0 += BK) {
        const u16 *ah, *al;
        int ld;
        if (k0 < EE) {
            ah = wch + (size_t)bm * EE + k0;
            al = wcl + (size_t)bm * EE + k0;
            ld = EE;
        } else {
            ah = dech + (size_t)bm * DDIM + (k0 - EE);
            al = decl + (size_t)bm * DDIM + (k0 - EE);
            ld = DDIM;
        }
        __syncthreads();
        stage_glds<BM>(Ah, ah, ld, tid);
        stage_glds<BM>(Al, al, ld, tid);
        stage_glds_b32(Bh, Bl, woth + (size_t)bn * (EE + DDIM) + k0,
                       wotl + (size_t)bn * (EE + DDIM) + k0, EE + DDIM, tid);
        __builtin_amdgcn_s_waitcnt(0);
        __syncthreads();
        mfma_ss41(Ah, Al, Bh, Bl, acc, tid);
    }
    const int lane = tid & 63, w = tid >> 6;
    const int wm = (w & 1) * 64, wn = (w >> 1) * 16;
    const int fr = lane & 15, q = lane >> 4;
    const int col = bn + wn + fr;
#pragma unroll
    for (int i = 0; i < 4; ++i)
#pragma unroll
        for (int r = 0; r < 4; ++r) {
            const int row = bm + wm + 16 * i + 4 * q + r;
            ht[(size_t)row * DDIM + col] = tanhf(acc[i][r]);
        }
}

// ---------------------------------------------------------------------------
extern "C" void kernel_launch(void* const* d_in, const int* in_sizes, int n_in,
                              void* d_out, int out_size, void* d_ws, size_t ws_size,
                              hipStream_t stream) {
    (void)in_sizes; (void)n_in; (void)out_size; (void)ws_size;
    const float* dec = (const float*)d_in[0];
    const float* enc = (const float*)d_in[1];
    const int* mask = (const int*)d_in[2];
    const float* Wa = (const float*)d_in[3];
    const float* ba = (const float*)d_in[4];
    const float* Wo = (const float*)d_in[5];

    float* h_tilde = (float*)d_out;
    float* attn = h_tilde + (size_t)BB * TT * DDIM;
    float* menerg = attn + (size_t)BB * TT * SS;

    // Workspace layout (bytes), total ~72.4 MB
    char* ws = (char*)d_ws;
    u16* decW_hi = (u16*)(ws);
    u16* decW_lo = (u16*)(ws + 16777216);
    u16* dec_hi  = (u16*)(ws + 33554432);
    u16* dec_lo  = (u16*)(ws + 41943040);
    u16* attn_hi = (u16*)(ws + 50331648);
    u16* attn_lo = (u16*)(ws + 58720256);
    u16* wa_hi   = (u16*)(ws + 67108864);
    u16* wa_lo   = (u16*)(ws + 68157440);
    u16* wot_hi  = (u16*)(ws + 69206016);
    u16* wot_lo  = (u16*)(ws + 70778880);
    float* decb  = (float*)(ws + 72351744);
    u16* wc_hi = decW_hi;
    u16* wc_lo = decW_lo;

    k_conv<<<(BB * TT * DDIM) / 4 / 256, 256, 0, stream>>>(dec, dec_hi, dec_lo);
    k_conv<<<(EE * DDIM) / 4 / 256, 256, 0, stream>>>(Wa, wa_hi, wa_lo);
    k_wot<<<dim3((EE + DDIM) / 64, DDIM / 64), 256, 0, stream>>>(Wo, wot_hi, wot_lo);
    k_decb<<<(BB * TT) / 4, 256, 0, stream>>>(dec, ba, decb);
    k_decw<<<dim3((BB * TT) / BM, EE / BN), 256, 0, stream>>>(dec_hi, dec_lo, wa_hi, wa_lo,
                                                              decW_hi, decW_lo);
    k_energy<<<dim3(SS / BNS, 1, BB), 256, 0, stream>>>(decW_hi, decW_lo, enc, mask, decb, menerg);
    k_softmax<<<BB * TT, 128, 0, stream>>>(menerg, attn, attn_hi, attn_lo);
    k_ctx<<<dim3(EE / BN, 1, BB), 256, 0, stream>>>(attn_hi, attn_lo, enc, wc_hi, wc_lo);
    k_out<<<dim3((BB * TT) / BM, DDIM / BNS), 256, 0, stream>>>(wc_hi, wc_lo, dec_hi, dec_lo,
                                                                wot_hi, wot_lo, h_tilde);
}